// Round 2
// baseline (635.700 us; speedup 1.0000x reference)
//
#include <hip/hip_runtime.h>
#include <hip/hip_bf16.h>

// GCN forward: conv1(GEMM + sym-norm agg) -> BN -> PReLU -> conv2(GEMM + agg)
// N=100000, E=1600000, DIN=128, 2H=128, H=64. fp32 in/out.
//
// R2 changes vs R1 (633 us):
//  - scatter_k (126 us, 105 MB write-allocate amplification) replaced by a
//    two-phase bucketed sort: bin by dst>>5 (sequential per-bucket writes ->
//    full 64B lines), then fine scatter inside ~2KB L2-resident windows.
//    Bucket cursors padded to 64B (kills same-line atomic serialization).
//  - agg1 gathers bf16 h (gemm1 emits bf16), halving its 435 MB fetch.
//    Accumulation stays fp32; BN renormalizes the ~0.4% bf16 error.

#define DIN 128
#define F1  128   // 2H
#define F2  64    // H
#define BN_EPS 1e-5f
#define BSHIFT 5  // 32 nodes per bucket

__device__ __forceinline__ unsigned short f2bf(float f) {
    unsigned int u = __float_as_uint(f);
    u = u + 0x7fffu + ((u >> 16) & 1u);   // RNE
    return (unsigned short)(u >> 16);
}
__device__ __forceinline__ float bf_lo(unsigned int v) { return __uint_as_float(v << 16); }
__device__ __forceinline__ float bf_hi(unsigned int v) { return __uint_as_float(v & 0xffff0000u); }

// ---------------- graph build ----------------

__global__ __launch_bounds__(256) void count_deg_k(const int* __restrict__ dst,
                                                   int* __restrict__ degi, int e) {
    int i = blockIdx.x * 256 + threadIdx.x;
    if (i < e) atomicAdd(&degi[dst[i]], 1);
}

__global__ __launch_bounds__(256) void dinv_k(const int* __restrict__ degi,
                                              float* __restrict__ dinv, int n) {
    int i = blockIdx.x * 256 + threadIdx.x;
    if (i < n) dinv[i] = rsqrtf((float)(degi[i] + 1));  // +1 self-loop
}

// scan phase A: per-chunk (4096) sums
__global__ __launch_bounds__(256) void scan_a_k(const int* __restrict__ deg,
                                                int* __restrict__ part, int n) {
    __shared__ int red[256];
    int b = blockIdx.x, t = threadIdx.x;
    int base = b * 4096 + t * 16;
    int s = 0;
#pragma unroll
    for (int i = 0; i < 16; i++) {
        int idx = base + i;
        s += (idx < n) ? deg[idx] : 0;
    }
    red[t] = s;
    __syncthreads();
    for (int ofs = 128; ofs > 0; ofs >>= 1) {
        if (t < ofs) red[t] += red[t + ofs];
        __syncthreads();
    }
    if (t == 0) part[b] = red[0];
}

// scan phase B: serial exclusive scan of partials, write rowptr[n]=E
__global__ void scan_b_k(int* part, int* rowptr, int nb, int n) {
    if (threadIdx.x == 0 && blockIdx.x == 0) {
        int run = 0;
        for (int b = 0; b < nb; b++) { int x = part[b]; part[b] = run; run += x; }
        rowptr[n] = run;
    }
}

// scan phase C: per-chunk exclusive scan + global offset -> rowptr, rowcur
__global__ __launch_bounds__(256) void scan_c_k(const int* __restrict__ deg,
                                                const int* __restrict__ part,
                                                int* __restrict__ rowptr,
                                                int* __restrict__ rowcur, int n) {
    __shared__ int sums[256];
    int b = blockIdx.x, t = threadIdx.x;
    int base = b * 4096 + t * 16;
    int loc[16];
    int s = 0;
#pragma unroll
    for (int i = 0; i < 16; i++) {
        int idx = base + i;
        int d = (idx < n) ? deg[idx] : 0;
        loc[i] = s;
        s += d;
    }
    sums[t] = s;
    __syncthreads();
    int run = s;
    for (int ofs = 1; ofs < 256; ofs <<= 1) {
        int y = (t >= ofs) ? sums[t - ofs] : 0;
        __syncthreads();
        run += y;
        sums[t] = run;
        __syncthreads();
    }
    int offb = part[b] + (run - s);
#pragma unroll
    for (int i = 0; i < 16; i++) {
        int idx = base + i;
        if (idx < n) {
            int v = offb + loc[i];
            rowptr[idx] = v;
            rowcur[idx] = v;
        }
    }
}

// bucket cursors = rowptr at bucket starts (padded 16 ints = 64B apart)
__global__ __launch_bounds__(256) void binit_k(const int* __restrict__ rowptr,
                                               int* __restrict__ bucketcur, int nbuck) {
    int b = blockIdx.x * 256 + threadIdx.x;
    if (b < nbuck) bucketcur[b * 16] = rowptr[b << BSHIFT];
}

// phase 1: bin (src,dst) by dst bucket — sequential writes per bucket
__global__ __launch_bounds__(256) void pass1_k(const int* __restrict__ src,
                                               const int* __restrict__ dst,
                                               int* __restrict__ bucketcur,
                                               int2* __restrict__ pairs, int e) {
    int i = blockIdx.x * 256 + threadIdx.x;
    if (i < e) {
        int s = src[i], d = dst[i];
        int pos = atomicAdd(&bucketcur[(d >> BSHIFT) * 16], 1);
        pairs[pos] = make_int2(s, d);
    }
}

// phase 2: fine scatter inside the (L2-resident) bucket window
__global__ __launch_bounds__(256) void pass2_k(const int2* __restrict__ pairs,
                                               int* __restrict__ rowcur,
                                               int* __restrict__ srcsorted, int e) {
    int i = blockIdx.x * 256 + threadIdx.x;
    if (i < e) {
        int2 p = pairs[i];
        int pos = atomicAdd(&rowcur[p.y], 1);
        srcsorted[pos] = p.x;
    }
}

// ---------------- GEMM1: h(bf16) = x @ W1  (N x 128 @ 128 x 128) ----------------

__global__ __launch_bounds__(256) void gemm1_k(const float* __restrict__ x,
                                               const float* __restrict__ W,
                                               unsigned int* __restrict__ h, int n) {
    __shared__ float xs[64][DIN];
    int t = threadIdx.x;
    int row0 = blockIdx.x * 64;
    const float4* x4 = (const float4*)x;
#pragma unroll
    for (int i = 0; i < 8; i++) {
        int l = t + i * 256;
        int r = l >> 5;
        int c = l & 31;
        float4 v = make_float4(0.f, 0.f, 0.f, 0.f);
        if (row0 + r < n) v = x4[(size_t)(row0 + r) * 32 + c];
        *(float4*)&xs[r][c * 4] = v;
    }
    __syncthreads();
    int cg = t & 31;
    int r0 = (t >> 5) * 8;
    float acc[8][4];
#pragma unroll
    for (int r = 0; r < 8; r++)
#pragma unroll
        for (int c = 0; c < 4; c++) acc[r][c] = 0.f;
    const float4* W4 = (const float4*)W;
#pragma unroll 4
    for (int k = 0; k < DIN; k++) {
        float4 bv = W4[k * 32 + cg];
#pragma unroll
        for (int r = 0; r < 8; r++) {
            float a = xs[r0 + r][k];
            acc[r][0] = fmaf(a, bv.x, acc[r][0]);
            acc[r][1] = fmaf(a, bv.y, acc[r][1]);
            acc[r][2] = fmaf(a, bv.z, acc[r][2]);
            acc[r][3] = fmaf(a, bv.w, acc[r][3]);
        }
    }
    uint2* h2v = (uint2*)h;
#pragma unroll
    for (int r = 0; r < 8; r++) {
        int row = row0 + r0 + r;
        if (row < n) {
            unsigned int p0 = (unsigned int)f2bf(acc[r][0]) | ((unsigned int)f2bf(acc[r][1]) << 16);
            unsigned int p1 = (unsigned int)f2bf(acc[r][2]) | ((unsigned int)f2bf(acc[r][3]) << 16);
            h2v[(size_t)row * 32 + cg] = make_uint2(p0, p1);
        }
    }
}

// -------- aggregation 1: z = D^-1/2 (A+I) D^-1/2 h + b1  (bf16 gather) --------

__global__ __launch_bounds__(64) void agg1_k(const unsigned int* __restrict__ h,  // bf16x2, 64/row
                                             const float* __restrict__ dinv,
                                             const int* __restrict__ rowptr,
                                             const int* __restrict__ srcs,
                                             const float* __restrict__ b1,
                                             float* __restrict__ z, int n) {
    int nd = blockIdx.x;
    int f = threadIdx.x;  // bf16-pair index, 0..63
    float di = dinv[nd];
    unsigned int sv = h[(size_t)nd * 64 + f];
    float ax = di * bf_lo(sv);
    float ay = di * bf_hi(sv);
    int e = rowptr[nd], e1 = rowptr[nd + 1];
    for (; e + 4 <= e1; e += 4) {
        int s0 = srcs[e], s1 = srcs[e + 1], s2 = srcs[e + 2], s3 = srcs[e + 3];
        float d0 = dinv[s0], d1 = dinv[s1], d2 = dinv[s2], d3 = dinv[s3];
        unsigned int v0 = h[(size_t)s0 * 64 + f];
        unsigned int v1 = h[(size_t)s1 * 64 + f];
        unsigned int v2 = h[(size_t)s2 * 64 + f];
        unsigned int v3 = h[(size_t)s3 * 64 + f];
        ax = fmaf(d0, bf_lo(v0), ax); ay = fmaf(d0, bf_hi(v0), ay);
        ax = fmaf(d1, bf_lo(v1), ax); ay = fmaf(d1, bf_hi(v1), ay);
        ax = fmaf(d2, bf_lo(v2), ax); ay = fmaf(d2, bf_hi(v2), ay);
        ax = fmaf(d3, bf_lo(v3), ax); ay = fmaf(d3, bf_hi(v3), ay);
    }
    for (; e < e1; e++) {
        int s = srcs[e];
        float ds = dinv[s];
        unsigned int v = h[(size_t)s * 64 + f];
        ax = fmaf(ds, bf_lo(v), ax);
        ay = fmaf(ds, bf_hi(v), ay);
    }
    float2 bb = ((const float2*)b1)[f];
    float2 o;
    o.x = fmaf(ax, di, bb.x);
    o.y = fmaf(ay, di, bb.y);
    ((float2*)z)[(size_t)nd * 64 + f] = o;
}

// ---------------- BatchNorm stats ----------------

__global__ __launch_bounds__(128) void bnstats_k(const float* __restrict__ z,
                                                 double* __restrict__ bnacc, int n) {
    int f = threadIdx.x;
    float s = 0.f, q = 0.f;
    for (int r = blockIdx.x; r < n; r += gridDim.x) {
        float v = z[(size_t)r * F1 + f];
        s += v;
        q = fmaf(v, v, q);
    }
    atomicAdd(&bnacc[f], (double)s);
    atomicAdd(&bnacc[F1 + f], (double)q);
}

__global__ __launch_bounds__(128) void bnfinal_k(const double* __restrict__ bnacc,
                                                 const float* __restrict__ gamma,
                                                 const float* __restrict__ beta,
                                                 float* __restrict__ scale,
                                                 float* __restrict__ shift, int n) {
    int f = threadIdx.x;
    double mean = bnacc[f] / n;
    double var = bnacc[F1 + f] / n - mean * mean;
    float sc = gamma[f] * rsqrtf((float)var + BN_EPS);
    scale[f] = sc;
    shift[f] = beta[f] - (float)mean * sc;
}

// ---------- GEMM2: h2 = prelu(bn(z)) @ W2  (N x 128 @ 128 x 64) ----------

__global__ __launch_bounds__(256) void gemm2_k(const float* __restrict__ z,
                                               const float* __restrict__ W,
                                               const float* __restrict__ scale,
                                               const float* __restrict__ shift,
                                               const float* __restrict__ prelu_a,
                                               float* __restrict__ h2, int n) {
    __shared__ float zs[64][F1];
    int t = threadIdx.x;
    int row0 = blockIdx.x * 64;
    float pa = prelu_a[0];
    const float4* z4 = (const float4*)z;
    const float4* sc4 = (const float4*)scale;
    const float4* sh4 = (const float4*)shift;
#pragma unroll
    for (int i = 0; i < 8; i++) {
        int l = t + i * 256;
        int r = l >> 5;
        int c = l & 31;
        float4 v = make_float4(0.f, 0.f, 0.f, 0.f);
        if (row0 + r < n) v = z4[(size_t)(row0 + r) * 32 + c];
        float4 sc = sc4[c], sh = sh4[c];
        v.x = fmaf(v.x, sc.x, sh.x); v.x = v.x >= 0.f ? v.x : pa * v.x;
        v.y = fmaf(v.y, sc.y, sh.y); v.y = v.y >= 0.f ? v.y : pa * v.y;
        v.z = fmaf(v.z, sc.z, sh.z); v.z = v.z >= 0.f ? v.z : pa * v.z;
        v.w = fmaf(v.w, sc.w, sh.w); v.w = v.w >= 0.f ? v.w : pa * v.w;
        *(float4*)&zs[r][c * 4] = v;
    }
    __syncthreads();
    int cg = t & 15;
    int r0 = (t >> 4) * 4;
    float acc[4][4];
#pragma unroll
    for (int r = 0; r < 4; r++)
#pragma unroll
        for (int c = 0; c < 4; c++) acc[r][c] = 0.f;
    const float4* W4 = (const float4*)W;
#pragma unroll 4
    for (int k = 0; k < F1; k++) {
        float4 bv = W4[k * 16 + cg];
#pragma unroll
        for (int r = 0; r < 4; r++) {
            float a = zs[r0 + r][k];
            acc[r][0] = fmaf(a, bv.x, acc[r][0]);
            acc[r][1] = fmaf(a, bv.y, acc[r][1]);
            acc[r][2] = fmaf(a, bv.z, acc[r][2]);
            acc[r][3] = fmaf(a, bv.w, acc[r][3]);
        }
    }
    float4* o4 = (float4*)h2;
#pragma unroll
    for (int r = 0; r < 4; r++) {
        int row = row0 + r0 + r;
        if (row < n)
            o4[(size_t)row * 16 + cg] = make_float4(acc[r][0], acc[r][1], acc[r][2], acc[r][3]);
    }
}

// ---------------- aggregation 2 -> output (fp32) ----------------

__global__ __launch_bounds__(64) void agg2_k(const float* __restrict__ h,
                                             const float* __restrict__ dinv,
                                             const int* __restrict__ rowptr,
                                             const int* __restrict__ srcs,
                                             const float* __restrict__ b2,
                                             float* __restrict__ out, int n) {
    int nd = blockIdx.x;
    int f = threadIdx.x;
    float di = dinv[nd];
    float acc = di * h[(size_t)nd * F2 + f];
    int e = rowptr[nd], e1 = rowptr[nd + 1];
    for (; e + 4 <= e1; e += 4) {
        int s0 = srcs[e], s1 = srcs[e + 1], s2 = srcs[e + 2], s3 = srcs[e + 3];
        float d0 = dinv[s0], d1 = dinv[s1], d2 = dinv[s2], d3 = dinv[s3];
        float h0 = h[(size_t)s0 * F2 + f];
        float h1 = h[(size_t)s1 * F2 + f];
        float h2 = h[(size_t)s2 * F2 + f];
        float h3 = h[(size_t)s3 * F2 + f];
        acc = fmaf(d0, h0, acc);
        acc = fmaf(d1, h1, acc);
        acc = fmaf(d2, h2, acc);
        acc = fmaf(d3, h3, acc);
    }
    for (; e < e1; e++) {
        int s = srcs[e];
        acc = fmaf(dinv[s], h[(size_t)s * F2 + f], acc);
    }
    out[(size_t)nd * F2 + f] = fmaf(acc, di, b2[f]);
}

// ---------------- launch ----------------

extern "C" void kernel_launch(void* const* d_in, const int* in_sizes, int n_in,
                              void* d_out, int out_size, void* d_ws, size_t ws_size,
                              hipStream_t stream) {
    const float* x       = (const float*)d_in[0];
    const int*   ei      = (const int*)d_in[1];
    const float* W1      = (const float*)d_in[2];
    const float* b1      = (const float*)d_in[3];
    const float* W2      = (const float*)d_in[4];
    const float* b2      = (const float*)d_in[5];
    const float* gamma   = (const float*)d_in[6];
    const float* beta    = (const float*)d_in[7];
    const float* prelu_a = (const float*)d_in[8];

    const int N = in_sizes[0] / DIN;
    const int E = in_sizes[1] / 2;
    const int* src = ei;
    const int* dst = ei + E;
    const int NBUCK = (N + (1 << BSHIFT) - 1) >> BSHIFT;

    char* p = (char*)d_ws;
    size_t off = 0;
    auto take = [&](size_t bytes) -> char* {
        char* r = p + off;
        off = (off + bytes + 255) & ~(size_t)255;
        return r;
    };
    int*          degi      = (int*)take((size_t)N * 4);
    float*        dinv      = (float*)take((size_t)N * 4);
    int*          rowptr    = (int*)take((size_t)(N + 1) * 4);
    int*          rowcur    = (int*)take((size_t)N * 4);
    int*          partials  = (int*)take(64 * 4);
    int*          bucketcur = (int*)take((size_t)NBUCK * 16 * 4);  // 64B-padded
    int*          srcsorted = (int*)take((size_t)E * 4);
    int2*         pairs     = (int2*)take((size_t)E * 8);
    double*       bnacc     = (double*)take(2 * F1 * 8);
    float*        scale     = (float*)take(F1 * 4);
    float*        shift     = (float*)take(F1 * 4);
    unsigned int* h         = (unsigned int*)take((size_t)N * 64 * 4);  // bf16 h, 64 uints/row
    float*        z         = (float*)take((size_t)N * F1 * 4);
    float*        h2        = (float*)h;  // h dead after agg1; same byte size (N*64*4)
    float*        out       = (float*)d_out;

    hipMemsetAsync(degi, 0, (size_t)N * 4, stream);
    hipMemsetAsync(bnacc, 0, 2 * F1 * 8, stream);

    const int eb = (E + 255) / 256;
    const int NB = (N + 4095) / 4096;

    count_deg_k<<<eb, 256, 0, stream>>>(dst, degi, E);
    dinv_k<<<(N + 255) / 256, 256, 0, stream>>>(degi, dinv, N);
    scan_a_k<<<NB, 256, 0, stream>>>(degi, partials, N);
    scan_b_k<<<1, 64, 0, stream>>>(partials, rowptr, NB, N);
    scan_c_k<<<NB, 256, 0, stream>>>(degi, partials, rowptr, rowcur, N);
    binit_k<<<(NBUCK + 255) / 256, 256, 0, stream>>>(rowptr, bucketcur, NBUCK);
    pass1_k<<<eb, 256, 0, stream>>>(src, dst, bucketcur, pairs, E);
    pass2_k<<<eb, 256, 0, stream>>>(pairs, rowcur, srcsorted, E);

    gemm1_k<<<(N + 63) / 64, 256, 0, stream>>>(x, W1, h, N);
    agg1_k<<<N, 64, 0, stream>>>(h, dinv, rowptr, srcsorted, b1, z, N);
    bnstats_k<<<512, F1, 0, stream>>>(z, bnacc, N);
    bnfinal_k<<<1, F1, 0, stream>>>(bnacc, gamma, beta, scale, shift, N);
    gemm2_k<<<(N + 63) / 64, 256, 0, stream>>>(z, W2, scale, shift, prelu_a, h2, N);
    agg2_k<<<N, F2, 0, stream>>>(h2, dinv, rowptr, srcsorted, b2, out, N);
}

// Round 3
// 425.272 us; speedup vs baseline: 1.4948x; 1.4948x over previous
//
#include <hip/hip_runtime.h>
#include <hip/hip_bf16.h>

// GCN forward: conv1(GEMM + sym-norm agg) -> BN -> PReLU -> conv2(GEMM + agg)
// N=100000, E=1600000, DIN=128, 2H=128, H=64. fp32 in/out.
//
// R3 changes vs R2 (635 us):
//  - Graph build rebuilt as block-local counting sort. R2's pass1 kept 91 MB
//    WRITE_SIZE: bucket cursors shared across XCDs -> lines partially dirtied
//    in 8 incoherent L2s -> full write-allocate amplification. Now every line
//    is written by exactly ONE workgroup:
//      hist_k    per-block LDS histogram of dst>>8 (replaces count_deg's 1.6M
//                random global atomics too)
//      bscan_k   1-block scan of 391 bucket counts
//      binpass_k block counting-sort of 8192-edge chunks; per-(block,bucket)
//                contiguous regions reserved with one atomic per bucket
//      bucket_k  one block per bucket: degrees/dinv/rowptr + fine scatter,
//                all atomics in LDS, 16KB single-block write window
//  - gemm2 emits bf16, agg2 gathers bf16 (halves its 410 MB gather).

#define DIN 128
#define F1  128   // 2H
#define F2  64    // H
#define BN_EPS 1e-5f
#define NODE_BSHIFT 8          // 256 nodes per bucket
#define NODE_BMASK  255
#define CHUNK 8192             // edges per binpass block

__device__ __forceinline__ unsigned short f2bf(float f) {
    unsigned int u = __float_as_uint(f);
    u = u + 0x7fffu + ((u >> 16) & 1u);   // RNE
    return (unsigned short)(u >> 16);
}
__device__ __forceinline__ float bf_lo(unsigned int v) { return __uint_as_float(v << 16); }
__device__ __forceinline__ float bf_hi(unsigned int v) { return __uint_as_float(v & 0xffff0000u); }
__device__ __forceinline__ float bfu(unsigned short u) { return __uint_as_float((unsigned int)u << 16); }

// ---------------- graph build ----------------

// per-block LDS histogram of dst buckets
__global__ __launch_bounds__(256) void hist_k(const int* __restrict__ dst,
                                              int* __restrict__ bucketcnt,
                                              int e, int nbuck) {
    __shared__ int lh[512];
    int t = threadIdx.x;
    for (int i = t; i < 512; i += 256) lh[i] = 0;
    __syncthreads();
    int base = blockIdx.x * CHUNK;
    int end = base + CHUNK; if (end > e) end = e;
    for (int i = base + t; i < end; i += 256)
        atomicAdd(&lh[dst[i] >> NODE_BSHIFT], 1);
    __syncthreads();
    for (int b = t; b < nbuck; b += 256) {
        int v = lh[b];
        if (v) atomicAdd(&bucketcnt[b], v);
    }
}

// one-block exclusive scan of bucket counts (nbuck <= 512)
__global__ __launch_bounds__(512) void bscan_k(const int* __restrict__ bucketcnt,
                                               int* __restrict__ bucketbase,
                                               int* __restrict__ bucketcur,
                                               int* __restrict__ rowptr,
                                               int nbuck, int n, int e) {
    __shared__ int s[512];
    int t = threadIdx.x;
    int orig = (t < nbuck) ? bucketcnt[t] : 0;
    s[t] = orig;
    __syncthreads();
    int run = orig;
    for (int ofs = 1; ofs < 512; ofs <<= 1) {
        int y = (t >= ofs) ? s[t - ofs] : 0;
        __syncthreads();
        run += y;
        s[t] = run;
        __syncthreads();
    }
    if (t < nbuck) {
        int excl = run - orig;
        bucketbase[t] = excl;
        bucketcur[t] = excl;
    }
    if (t == 0) {
        bucketbase[nbuck] = e;
        rowptr[n] = e;
    }
}

// block counting-sort: chunk of edges -> bucket-grouped (src,dst) pairs.
// All writes to a pairs[] line come from this block (one XCD's L2).
__global__ __launch_bounds__(256) void binpass_k(const int* __restrict__ src,
                                                 const int* __restrict__ dst,
                                                 int* __restrict__ bucketcur,
                                                 int2* __restrict__ pairs, int e) {
    __shared__ int lh[512], lbase[512], lrank[512];
    int t = threadIdx.x;
    for (int i = t; i < 512; i += 256) { lh[i] = 0; lrank[i] = 0; }
    __syncthreads();
    int base = blockIdx.x * CHUNK;
    int end = base + CHUNK; if (end > e) end = e;
    for (int i = base + t; i < end; i += 256)
        atomicAdd(&lh[dst[i] >> NODE_BSHIFT], 1);
    __syncthreads();
    for (int b = t; b < 512; b += 256) {
        int v = lh[b];
        lbase[b] = v ? atomicAdd(&bucketcur[b], v) : 0;
    }
    __syncthreads();
    for (int i = base + t; i < end; i += 256) {
        int sv = src[i], dv = dst[i];
        int b = dv >> NODE_BSHIFT;
        int r = atomicAdd(&lrank[b], 1);
        pairs[lbase[b] + r] = make_int2(sv, dv);
    }
}

// one block per bucket: per-node degree -> dinv + rowptr, then fine scatter
// of src into the bucket's (single-block, L2-local) srcsorted window.
__global__ __launch_bounds__(256) void bucket_k(const int2* __restrict__ pairs,
                                                const int* __restrict__ bucketbase,
                                                float* __restrict__ dinv,
                                                int* __restrict__ rowptr,
                                                int* __restrict__ srcsorted, int n) {
    __shared__ int lh[256], loff[256], lrank[256];
    int b = blockIdx.x, t = threadIdx.x;
    int e0 = bucketbase[b], e1 = bucketbase[b + 1];
    lh[t] = 0;
    lrank[t] = 0;
    __syncthreads();
    for (int i = e0 + t; i < e1; i += 256)
        atomicAdd(&lh[pairs[i].y & NODE_BMASK], 1);
    __syncthreads();
    int deg = lh[t];
    int run = deg;
    for (int ofs = 1; ofs < 256; ofs <<= 1) {
        int y = (t >= ofs) ? lh[t - ofs] : 0;
        __syncthreads();
        run += y;
        lh[t] = run;
        __syncthreads();
    }
    loff[t] = run - deg;
    int node = (b << NODE_BSHIFT) + t;
    if (node < n) {
        dinv[node] = rsqrtf((float)(deg + 1));   // +1 self-loop
        rowptr[node] = e0 + (run - deg);
    }
    __syncthreads();
    for (int i = e0 + t; i < e1; i += 256) {
        int2 p = pairs[i];
        int lo = p.y & NODE_BMASK;
        int r = atomicAdd(&lrank[lo], 1);
        srcsorted[e0 + loff[lo] + r] = p.x;
    }
}

// ---------------- GEMM1: h(bf16) = x @ W1  (N x 128 @ 128 x 128) ----------------

__global__ __launch_bounds__(256) void gemm1_k(const float* __restrict__ x,
                                               const float* __restrict__ W,
                                               unsigned int* __restrict__ h, int n) {
    __shared__ float xs[64][DIN];
    int t = threadIdx.x;
    int row0 = blockIdx.x * 64;
    const float4* x4 = (const float4*)x;
#pragma unroll
    for (int i = 0; i < 8; i++) {
        int l = t + i * 256;
        int r = l >> 5;
        int c = l & 31;
        float4 v = make_float4(0.f, 0.f, 0.f, 0.f);
        if (row0 + r < n) v = x4[(size_t)(row0 + r) * 32 + c];
        *(float4*)&xs[r][c * 4] = v;
    }
    __syncthreads();
    int cg = t & 31;
    int r0 = (t >> 5) * 8;
    float acc[8][4];
#pragma unroll
    for (int r = 0; r < 8; r++)
#pragma unroll
        for (int c = 0; c < 4; c++) acc[r][c] = 0.f;
    const float4* W4 = (const float4*)W;
#pragma unroll 4
    for (int k = 0; k < DIN; k++) {
        float4 bv = W4[k * 32 + cg];
#pragma unroll
        for (int r = 0; r < 8; r++) {
            float a = xs[r0 + r][k];
            acc[r][0] = fmaf(a, bv.x, acc[r][0]);
            acc[r][1] = fmaf(a, bv.y, acc[r][1]);
            acc[r][2] = fmaf(a, bv.z, acc[r][2]);
            acc[r][3] = fmaf(a, bv.w, acc[r][3]);
        }
    }
    uint2* h2v = (uint2*)h;
#pragma unroll
    for (int r = 0; r < 8; r++) {
        int row = row0 + r0 + r;
        if (row < n) {
            unsigned int p0 = (unsigned int)f2bf(acc[r][0]) | ((unsigned int)f2bf(acc[r][1]) << 16);
            unsigned int p1 = (unsigned int)f2bf(acc[r][2]) | ((unsigned int)f2bf(acc[r][3]) << 16);
            h2v[(size_t)row * 32 + cg] = make_uint2(p0, p1);
        }
    }
}

// -------- aggregation 1: z = D^-1/2 (A+I) D^-1/2 h + b1  (bf16 gather) --------

__global__ __launch_bounds__(64) void agg1_k(const unsigned int* __restrict__ h,  // bf16x2, 64/row
                                             const float* __restrict__ dinv,
                                             const int* __restrict__ rowptr,
                                             const int* __restrict__ srcs,
                                             const float* __restrict__ b1,
                                             float* __restrict__ z, int n) {
    int nd = blockIdx.x;
    int f = threadIdx.x;  // bf16-pair index, 0..63
    float di = dinv[nd];
    unsigned int sv = h[(size_t)nd * 64 + f];
    float ax = di * bf_lo(sv);
    float ay = di * bf_hi(sv);
    int e = rowptr[nd], e1 = rowptr[nd + 1];
    for (; e + 4 <= e1; e += 4) {
        int s0 = srcs[e], s1 = srcs[e + 1], s2 = srcs[e + 2], s3 = srcs[e + 3];
        float d0 = dinv[s0], d1 = dinv[s1], d2 = dinv[s2], d3 = dinv[s3];
        unsigned int v0 = h[(size_t)s0 * 64 + f];
        unsigned int v1 = h[(size_t)s1 * 64 + f];
        unsigned int v2 = h[(size_t)s2 * 64 + f];
        unsigned int v3 = h[(size_t)s3 * 64 + f];
        ax = fmaf(d0, bf_lo(v0), ax); ay = fmaf(d0, bf_hi(v0), ay);
        ax = fmaf(d1, bf_lo(v1), ax); ay = fmaf(d1, bf_hi(v1), ay);
        ax = fmaf(d2, bf_lo(v2), ax); ay = fmaf(d2, bf_hi(v2), ay);
        ax = fmaf(d3, bf_lo(v3), ax); ay = fmaf(d3, bf_hi(v3), ay);
    }
    for (; e < e1; e++) {
        int s = srcs[e];
        float ds = dinv[s];
        unsigned int v = h[(size_t)s * 64 + f];
        ax = fmaf(ds, bf_lo(v), ax);
        ay = fmaf(ds, bf_hi(v), ay);
    }
    float2 bb = ((const float2*)b1)[f];
    float2 o;
    o.x = fmaf(ax, di, bb.x);
    o.y = fmaf(ay, di, bb.y);
    ((float2*)z)[(size_t)nd * 64 + f] = o;
}

// ---------------- BatchNorm stats ----------------

__global__ __launch_bounds__(128) void bnstats_k(const float* __restrict__ z,
                                                 double* __restrict__ bnacc, int n) {
    int f = threadIdx.x;
    float s = 0.f, q = 0.f;
    for (int r = blockIdx.x; r < n; r += gridDim.x) {
        float v = z[(size_t)r * F1 + f];
        s += v;
        q = fmaf(v, v, q);
    }
    atomicAdd(&bnacc[f], (double)s);
    atomicAdd(&bnacc[F1 + f], (double)q);
}

__global__ __launch_bounds__(128) void bnfinal_k(const double* __restrict__ bnacc,
                                                 const float* __restrict__ gamma,
                                                 const float* __restrict__ beta,
                                                 float* __restrict__ scale,
                                                 float* __restrict__ shift, int n) {
    int f = threadIdx.x;
    double mean = bnacc[f] / n;
    double var = bnacc[F1 + f] / n - mean * mean;
    float sc = gamma[f] * rsqrtf((float)var + BN_EPS);
    scale[f] = sc;
    shift[f] = beta[f] - (float)mean * sc;
}

// ---- GEMM2: h2(bf16) = prelu(bn(z)) @ W2  (N x 128 @ 128 x 64) ----

__global__ __launch_bounds__(256) void gemm2_k(const float* __restrict__ z,
                                               const float* __restrict__ W,
                                               const float* __restrict__ scale,
                                               const float* __restrict__ shift,
                                               const float* __restrict__ prelu_a,
                                               unsigned short* __restrict__ h2, int n) {
    __shared__ float zs[64][F1];
    int t = threadIdx.x;
    int row0 = blockIdx.x * 64;
    float pa = prelu_a[0];
    const float4* z4 = (const float4*)z;
    const float4* sc4 = (const float4*)scale;
    const float4* sh4 = (const float4*)shift;
#pragma unroll
    for (int i = 0; i < 8; i++) {
        int l = t + i * 256;
        int r = l >> 5;
        int c = l & 31;
        float4 v = make_float4(0.f, 0.f, 0.f, 0.f);
        if (row0 + r < n) v = z4[(size_t)(row0 + r) * 32 + c];
        float4 sc = sc4[c], sh = sh4[c];
        v.x = fmaf(v.x, sc.x, sh.x); v.x = v.x >= 0.f ? v.x : pa * v.x;
        v.y = fmaf(v.y, sc.y, sh.y); v.y = v.y >= 0.f ? v.y : pa * v.y;
        v.z = fmaf(v.z, sc.z, sh.z); v.z = v.z >= 0.f ? v.z : pa * v.z;
        v.w = fmaf(v.w, sc.w, sh.w); v.w = v.w >= 0.f ? v.w : pa * v.w;
        *(float4*)&zs[r][c * 4] = v;
    }
    __syncthreads();
    int cg = t & 15;
    int r0 = (t >> 4) * 4;
    float acc[4][4];
#pragma unroll
    for (int r = 0; r < 4; r++)
#pragma unroll
        for (int c = 0; c < 4; c++) acc[r][c] = 0.f;
    const float4* W4 = (const float4*)W;
#pragma unroll 4
    for (int k = 0; k < F1; k++) {
        float4 bv = W4[k * 16 + cg];
#pragma unroll
        for (int r = 0; r < 4; r++) {
            float a = zs[r0 + r][k];
            acc[r][0] = fmaf(a, bv.x, acc[r][0]);
            acc[r][1] = fmaf(a, bv.y, acc[r][1]);
            acc[r][2] = fmaf(a, bv.z, acc[r][2]);
            acc[r][3] = fmaf(a, bv.w, acc[r][3]);
        }
    }
    uint2* o2 = (uint2*)h2;
#pragma unroll
    for (int r = 0; r < 4; r++) {
        int row = row0 + r0 + r;
        if (row < n) {
            unsigned int p0 = (unsigned int)f2bf(acc[r][0]) | ((unsigned int)f2bf(acc[r][1]) << 16);
            unsigned int p1 = (unsigned int)f2bf(acc[r][2]) | ((unsigned int)f2bf(acc[r][3]) << 16);
            o2[(size_t)row * 16 + cg] = make_uint2(p0, p1);
        }
    }
}

// ------------ aggregation 2 -> output (bf16 gather, fp32 out) ------------

__global__ __launch_bounds__(64) void agg2_k(const unsigned short* __restrict__ hs,  // bf16, 64/row
                                             const float* __restrict__ dinv,
                                             const int* __restrict__ rowptr,
                                             const int* __restrict__ srcs,
                                             const float* __restrict__ b2,
                                             float* __restrict__ out, int n) {
    int nd = blockIdx.x;
    int f = threadIdx.x;
    float di = dinv[nd];
    float acc = di * bfu(hs[(size_t)nd * F2 + f]);
    int e = rowptr[nd], e1 = rowptr[nd + 1];
    for (; e + 4 <= e1; e += 4) {
        int s0 = srcs[e], s1 = srcs[e + 1], s2 = srcs[e + 2], s3 = srcs[e + 3];
        float d0 = dinv[s0], d1 = dinv[s1], d2 = dinv[s2], d3 = dinv[s3];
        float h0 = bfu(hs[(size_t)s0 * F2 + f]);
        float h1 = bfu(hs[(size_t)s1 * F2 + f]);
        float h2 = bfu(hs[(size_t)s2 * F2 + f]);
        float h3 = bfu(hs[(size_t)s3 * F2 + f]);
        acc = fmaf(d0, h0, acc);
        acc = fmaf(d1, h1, acc);
        acc = fmaf(d2, h2, acc);
        acc = fmaf(d3, h3, acc);
    }
    for (; e < e1; e++) {
        int s = srcs[e];
        acc = fmaf(dinv[s], bfu(hs[(size_t)s * F2 + f]), acc);
    }
    out[(size_t)nd * F2 + f] = fmaf(acc, di, b2[f]);
}

// ---------------- launch ----------------

extern "C" void kernel_launch(void* const* d_in, const int* in_sizes, int n_in,
                              void* d_out, int out_size, void* d_ws, size_t ws_size,
                              hipStream_t stream) {
    const float* x       = (const float*)d_in[0];
    const int*   ei      = (const int*)d_in[1];
    const float* W1      = (const float*)d_in[2];
    const float* b1      = (const float*)d_in[3];
    const float* W2      = (const float*)d_in[4];
    const float* b2      = (const float*)d_in[5];
    const float* gamma   = (const float*)d_in[6];
    const float* beta    = (const float*)d_in[7];
    const float* prelu_a = (const float*)d_in[8];

    const int N = in_sizes[0] / DIN;
    const int E = in_sizes[1] / 2;
    const int* src = ei;
    const int* dst = ei + E;
    const int NBUCK = (N + NODE_BMASK) >> NODE_BSHIFT;  // 391 for N=100000

    char* p = (char*)d_ws;
    size_t off = 0;
    auto take = [&](size_t bytes) -> char* {
        char* r = p + off;
        off = (off + bytes + 255) & ~(size_t)255;
        return r;
    };
    int*            bucketcnt  = (int*)take(512 * 4);
    int*            bucketbase = (int*)take(513 * 4);
    int*            bucketcur  = (int*)take(512 * 4);
    float*          dinv       = (float*)take((size_t)N * 4);
    int*            rowptr     = (int*)take((size_t)(N + 1) * 4);
    int*            srcsorted  = (int*)take((size_t)E * 4);
    int2*           pairs      = (int2*)take((size_t)E * 8);
    double*         bnacc      = (double*)take(2 * F1 * 8);
    float*          scale      = (float*)take(F1 * 4);
    float*          shift      = (float*)take(F1 * 4);
    unsigned int*   h          = (unsigned int*)take((size_t)N * 64 * 4);  // bf16 h (128 feats)
    float*          z          = (float*)take((size_t)N * F1 * 4);
    unsigned short* h2         = (unsigned short*)h;  // h dead after agg1; bf16 h2 (64 feats)
    float*          out        = (float*)d_out;

    hipMemsetAsync(bucketcnt, 0, 512 * 4, stream);
    hipMemsetAsync(bnacc, 0, 2 * F1 * 8, stream);

    const int eb = (E + CHUNK - 1) / CHUNK;

    hist_k<<<eb, 256, 0, stream>>>(dst, bucketcnt, E, NBUCK);
    bscan_k<<<1, 512, 0, stream>>>(bucketcnt, bucketbase, bucketcur, rowptr, NBUCK, N, E);
    binpass_k<<<eb, 256, 0, stream>>>(src, dst, bucketcur, pairs, E);
    bucket_k<<<NBUCK, 256, 0, stream>>>(pairs, bucketbase, dinv, rowptr, srcsorted, N);

    gemm1_k<<<(N + 63) / 64, 256, 0, stream>>>(x, W1, h, N);
    agg1_k<<<N, 64, 0, stream>>>(h, dinv, rowptr, srcsorted, b1, z, N);
    bnstats_k<<<512, F1, 0, stream>>>(z, bnacc, N);
    bnfinal_k<<<1, F1, 0, stream>>>(bnacc, gamma, beta, scale, shift, N);
    gemm2_k<<<(N + 63) / 64, 256, 0, stream>>>(z, W2, scale, shift, prelu_a, h2, N);
    agg2_k<<<N, F2, 0, stream>>>(h2, dinv, rowptr, srcsorted, b2, out, N);
}